// Round 7
// baseline (1266.068 us; speedup 1.0000x reference)
//
#include <hip/hip_runtime.h>

// RNN car-following: NVEH=16384, NT=256, H=20.
// R7: WAVE-PAIR split of R6's operand-swapped structure. Block = 128 thr =
// 2 waves sharing 16 vehicles -> 1024 blocks = 2048 waves = 2/SIMD (R6 was
// 1/SIMD, latency-exposed: VALUBusy 50%, step 2190cy vs ~1100cy issue).
// Wave A: tiles 0-2 (j=0..11) + tile5; wave B: tiles 3-4 (j=12..19) + tile5
// + pos/spd/x/lead/out. Both get acc locally from tile 5 (identical rows
// bf16(7Wd); k=24/k=25 = 1.0 pick up wave A/B fp32 residual partials -> the
// MFMA does the cross-wave acc sum). Double-buffered aug, ONE 2-wave
// __syncthreads per step. Numerics = R5/R6 proven scheme (fp32 wc feedback,
// lagged virtual state, bf16 h/x + residual slot).

#define NVEH 16384
#define NT   256
#define H    20

typedef float f32x4  __attribute__((ext_vector_type(4)));
typedef short bf16x8 __attribute__((ext_vector_type(8)));
typedef short bf16x4 __attribute__((ext_vector_type(4)));

#if __has_builtin(__builtin_amdgcn_exp2f)
#define EXP2(x) __builtin_amdgcn_exp2f(x)
#else
#define EXP2(x) __expf((x) * 0.69314718056f)
#endif

__device__ __forceinline__ short f2bf(float f) {     // RNE float->bf16
    unsigned u = __builtin_bit_cast(unsigned, f);
    u += 0x7fffu + ((u >> 16) & 1u);
    return (short)(u >> 16);
}
__device__ __forceinline__ float bf2f(short s) {
    return __builtin_bit_cast(float, ((unsigned)(unsigned short)s) << 16);
}
// sigmoid of a pre-scaled (x*log2e) argument: 1/(1+2^-x)
__device__ __forceinline__ float sig2(float x) {
    return __builtin_amdgcn_rcpf(1.f + EXP2(-x));
}
// RNE-round to bf16: rounded fp32 (hi) + bf16 bits (hb)
__device__ __forceinline__ void rndbf(float v, float& hi, short& hb) {
    unsigned u = __builtin_bit_cast(unsigned, v);
    unsigned r = (u + 0x7fffu + ((u >> 16) & 1u)) & 0xffff0000u;
    hi = __builtin_bit_cast(float, r);
    hb = (short)(r >> 16);
}

__global__ __launch_bounds__(128, 2) void rnncf_kernel(
    const float* __restrict__ lead,   // (NVEH, NT, 2)
    const float* __restrict__ inits,  // (NVEH, 2)
    const float* __restrict__ h0,     // (NVEH, H)
    const float* __restrict__ c0,     // (NVEH, H)
    const float* __restrict__ W,      // (3, 80)
    const float* __restrict__ U,      // (20, 80)
    const float* __restrict__ b,      // (80,)
    const float* __restrict__ Wd,     // (20,)
    const float* __restrict__ bd,     // (1,)
    float* __restrict__ out)
{
    // UT rows 0..79: weight tiles, row T*16+m = gate(m&3) of col j=4T+(m>>2),
    // scaled log2e (2*log2e for gate g). Rows 80..95 (tile 5): identical:
    // bf16(7*Wd) k<20; 1.0 at k=24 (res_A) and k=25 (res_B).
    __shared__ __attribute__((aligned(16))) short UT[96 * 32];
    // aug double buffer: 16 veh x 40 shorts. k: 0..19 h, 20..22 x, 23 one,
    // 24 resA, 25 resB, 26..31 zero.
    __shared__ __attribute__((aligned(16))) short aug[2][16 * 40];
    __shared__ float scr[16];

    const int tid  = threadIdx.x;
    const int wv   = tid >> 6;        // 0 = wave A, 1 = wave B
    const int lane = tid & 63;
    const int q    = lane >> 4;       // k-slice / item j-offset
    const int c    = lane & 15;       // vehicle column
    const float L2E = 1.44269504f;
    const float bdv = bd[0];
    const float biasK = 7.f * bdv - 4.f;

    // ---- build UT ----
    for (int idx = tid; idx < 96 * 32; idx += 128) {
        int row = idx >> 5, k = idx & 31;
        float v = 0.f;
        if (row < 80) {
            int T = row >> 4, m = row & 15;
            int g = m & 3, j = 4 * T + (m >> 2);
            int col = g * 20 + j;
            if      (k < 20)  v = U[k * 80 + col];
            else if (k < 23)  v = W[(k - 20) * 80 + col];
            else if (k == 23) v = b[col];
            v *= (g == 2) ? (2.f * L2E) : L2E;
        } else {
            if      (k < 20)            v = 7.f * Wd[k];
            else if (k == 24 || k == 25) v = 1.f;
        }
        UT[idx] = f2bf(v);
    }
    for (int idx = tid; idx < 2 * 640; idx += 128)
        ((short*)aug)[idx] = 0;

    const int veh   = blockIdx.x * 16 + c;
    const int nT    = 3 - wv;         // A: 3 items/lane, B: 2
    const int Tbase = wv ? 3 : 0;

    // ---- per-item constants ----
    float wca[3][4], wd7[3], wdd[3];
#pragma unroll 3
    for (int T = 0; T < nT; ++T) {
        int j = 4 * (Tbase + T) + q;
#pragma unroll
        for (int g = 0; g < 4; ++g) {
            int col = g * 20 + j;
            wca[T][g] = (-0.001f * W[col] + 0.0025f * W[80 + col])
                      * ((g == 2) ? (2.f * L2E) : L2E);
        }
        float w7 = 7.f * Wd[j];
        wd7[T] = w7;
        wdd[T] = w7 - bf2f(f2bf(w7));
    }

    // ---- init: h0 -> buf0 (own items), res partial ----
    float cst[3], hl[3];
    float rpart = 0.f;
#pragma unroll 3
    for (int T = 0; T < nT; ++T) {
        int j = 4 * (Tbase + T) + q;
        float hv = h0[veh * H + j];
        cst[T] = c0[veh * H + j];
        hl[T] = hv;
        float hi; short hb;
        rndbf(hv, hi, hb);
        aug[0][c * 40 + j] = hb;
        rpart += (hv - hi) * wd7[T] + hi * wdd[T];
    }
    rpart += __shfl_xor(rpart, 16); rpart += __shfl_xor(rpart, 32);
    if (q == 0) aug[0][c * 40 + 24 + wv] = f2bf(rpart);

    // ---- wave B: scalar state, virtual lag, x_0 ----
    float pos = 0.f, spd = 0.f;
    const float2* lead2 = (const float2*)lead;
    float2 l2 = {0.f, 0.f};
    if (wv) {
        pos = inits[veh * 2 + 0];
        spd = inits[veh * 2 + 1];
        float ap = 0.f;
        for (int j = q; j < 20; j += 4) ap += h0[veh * H + j] * 7.f * Wd[j];
        ap += __shfl_xor(ap, 16); ap += __shfl_xor(ap, 32);
        float a = ap + biasK;                 // acc_{-1}, exact fp32
        pos -= 0.1f * a;                      // virtual lagged state
        spd -= 0.1f * a;
        if (q == 0) {
            l2 = lead2[(long)veh * NT];
            bf16x4 xs = { f2bf((l2.x - pos) * 0.01f), f2bf(spd * 0.025f),
                          f2bf(l2.y * 0.025f), f2bf(1.f) };
            *(bf16x4*)&aug[0][c * 40 + 20] = xs;
        }
    }
    __syncthreads();

    // ---- loop-invariant A fragments ----
    bf16x8 AF[3], AF5;
#pragma unroll 3
    for (int T = 0; T < nT; ++T)
        AF[T] = *(const bf16x8*)&UT[((Tbase + T) * 16 + c) * 32 + q * 8];
    AF5 = *(const bf16x8*)&UT[(80 + c) * 32 + q * 8];

    const int augB = c * 40 + q * 8;

    for (int t = 0; t < NT; ++t) {
        const short* rb = aug[t & 1];
        short* wb = (short*)aug[(t & 1) ^ 1];

        if (wv && q == 0) {   // prefetch lead[t+1]
            int tn = (t < NT - 1) ? t + 1 : t;
            l2 = lead2[(long)veh * NT + tn];
        }

        bf16x8 Bf = *(const bf16x8*)&rb[augB];
        f32x4 zero = {0.f, 0.f, 0.f, 0.f};
        f32x4 z[3];
#pragma unroll 3
        for (int T = 0; T < nT; ++T)
            z[T] = __builtin_amdgcn_mfma_f32_16x16x32_bf16(AF[T], Bf, zero, 0, 0, 0);
        f32x4 z5 = __builtin_amdgcn_mfma_f32_16x16x32_bf16(AF5, Bf, zero, 0, 0, 0);

        float acc = z5[0] + biasK;            // acc_{t-1}, every lane, fp32-acc

        if (wv) {
            pos += 0.1f * acc;
            spd += 0.1f * acc;
            if (q == 1 && t > 0)
                out[(t - 1) * NVEH + veh] = pos;
            if (q == 0) {   // x~ for step t+1
                bf16x4 xs = { f2bf((l2.x - pos) * 0.01f), f2bf(spd * 0.025f),
                              f2bf(l2.y * 0.025f), f2bf(1.f) };
                *(bf16x4*)&wb[c * 40 + 20] = xs;
            }
        }

        float rpt = 0.f;
#pragma unroll 3
        for (int T = 0; T < nT; ++T) {
            float ii = sig2(z[T][0] + acc * wca[T][0]);
            float ff = sig2(z[T][1] + acc * wca[T][1]);
            float gg = 2.f * sig2(z[T][2] + acc * wca[T][2]) - 1.f;  // tanh(g)
            float oo = sig2(z[T][3] + acc * wca[T][3]);
            float cc = ff * cst[T] + ii * gg;
            cst[T] = cc;
            float hh = oo * (2.f * sig2(2.f * L2E * cc) - 1.f);      // o*tanh(c)
            hl[T] = hh;
            float hi; short hb;
            rndbf(hh, hi, hb);
            wb[c * 40 + 4 * (Tbase + T) + q] = hb;
            rpt += (hh - hi) * wd7[T] + hi * wdd[T];
        }
        rpt += __shfl_xor(rpt, 16); rpt += __shfl_xor(rpt, 32);
        if (q == 0) wb[c * 40 + 24 + wv] = f2bf(rpt);

        __syncthreads();   // the ONE per-step barrier (2 waves)
    }

    // ---- tail: acc_255 exact from fp32 hl (cross-wave via scr) ----
    float ap = 0.f;
#pragma unroll 3
    for (int T = 0; T < nT; ++T) ap += hl[T] * wd7[T];
    ap += __shfl_xor(ap, 16); ap += __shfl_xor(ap, 32);
    if (!wv && q == 0) scr[c] = ap;
    __syncthreads();
    if (wv) {
        float accF = ap + scr[c] + biasK;
        if (q == 1) out[(NT - 1) * NVEH + veh] = pos + 0.1f * accF;
        if (q == 2) out[NT * NVEH + veh]       = spd + 0.1f * accF;
    }

    // ---- final h, c ----
    const int oH = NT * NVEH + NVEH;
    const int oC = oH + NVEH * H;
#pragma unroll 3
    for (int T = 0; T < nT; ++T) {
        int j = 4 * (Tbase + T) + q;
        out[oH + veh * H + j] = hl[T];
        out[oC + veh * H + j] = cst[T];
    }
}

extern "C" void kernel_launch(void* const* d_in, const int* in_sizes, int n_in,
                              void* d_out, int out_size, void* d_ws, size_t ws_size,
                              hipStream_t stream) {
    const float* lead  = (const float*)d_in[0];
    const float* inits = (const float*)d_in[1];
    const float* h0    = (const float*)d_in[2];
    const float* c0    = (const float*)d_in[3];
    const float* W     = (const float*)d_in[4];
    const float* U     = (const float*)d_in[5];
    const float* b     = (const float*)d_in[6];
    const float* Wd    = (const float*)d_in[7];
    const float* bd    = (const float*)d_in[8];
    float* out = (float*)d_out;

    rnncf_kernel<<<NVEH / 16, 128, 0, stream>>>(lead, inits, h0, c0, W, U, b, Wd, bd, out);
}

// Round 8
// 278.045 us; speedup vs baseline: 4.5535x; 4.5535x over previous
//
#include <hip/hip_runtime.h>

// RNN car-following: NVEH=16384, NT=256, H=20.
// R8: R6 backbone (weights=A, activations=B, 16 veh/wave, NO barrier, NO
// per-step cross-wave coupling — R7 proved per-step __syncthreads drains
// vmcnt and costs 5x). Changes vs R6, all aimed at the serial chain:
//  - shuffle-free residual: lane (q,c) writes its own fp32 partial (bf16)
//    at k=24+q; tile-5 A-rows have 1.0 at k=24..27 so the MFMA does the
//    cross-q sum (removes 2 serialized __shfl_xor per step).
//  - fma-folded sigmoid args, 2-instr res update, bfe/add3 RNE rounding.
//  - uniform t-addressing via row pointers (SALU), launch_bounds(256,1).
// Numerics otherwise identical to R5/R6 (passed, absmax 1.0).

#define NVEH 16384
#define NT   256
#define H    20

typedef float f32x4  __attribute__((ext_vector_type(4)));
typedef short bf16x8 __attribute__((ext_vector_type(8)));
typedef short bf16x4 __attribute__((ext_vector_type(4)));

#if __has_builtin(__builtin_amdgcn_exp2f)
#define EXP2(x) __builtin_amdgcn_exp2f(x)
#else
#define EXP2(x) __expf((x) * 0.69314718056f)
#endif
#define RCP(x) __builtin_amdgcn_rcpf(x)

__device__ __forceinline__ short f2bf(float f) {     // RNE float->bf16
    unsigned u = __builtin_bit_cast(unsigned, f);
    u += 0x7fffu + ((u >> 16) & 1u);
    return (short)(u >> 16);
}
__device__ __forceinline__ float bf2f(short s) {
    return __builtin_bit_cast(float, ((unsigned)(unsigned short)s) << 16);
}

__global__ __launch_bounds__(256, 1) void rnncf_kernel(
    const float* __restrict__ lead,   // (NVEH, NT, 2)
    const float* __restrict__ inits,  // (NVEH, 2)
    const float* __restrict__ h0,     // (NVEH, H)
    const float* __restrict__ c0,     // (NVEH, H)
    const float* __restrict__ W,      // (3, 80)
    const float* __restrict__ U,      // (20, 80)
    const float* __restrict__ b,      // (80,)
    const float* __restrict__ Wd,     // (20,)
    const float* __restrict__ bd,     // (1,)
    float* __restrict__ out)
{
    // UT rows 0..79: weight tiles 0..4, row T*16+m = gate(m&3) of col
    // j=4T+(m>>2), scaled log2e (2*log2e for gate g). Rows 80..95 (tile 5),
    // identical: bf16(7*Wd) at k<20, 1.0 at k=24..27 (per-q res slots).
    __shared__ __attribute__((aligned(16))) short UT[96 * 32];
    // aug: 16 veh x 40 shorts. k: 0..19 h(bf16), 20..22 x, 23 one,
    // 24..27 res_q, 28..31 zero.
    __shared__ __attribute__((aligned(16))) short aug[4][16 * 40];

    const int tid  = threadIdx.x;
    const int wv   = tid >> 6;
    const int lane = tid & 63;
    const int q    = lane >> 4;       // k-slice
    const int c    = lane & 15;       // vehicle column
    const float L2E = 1.44269504f;
    const float N2L = -2.f * L2E;
    const float bdv = bd[0];
    const float biasK = 7.f * bdv - 4.f;

    // ---- build UT ----
    for (int idx = tid; idx < 96 * 32; idx += 256) {
        int row = idx >> 5, k = idx & 31;
        float v = 0.f;
        if (row < 80) {
            int T = row >> 4, m = row & 15;
            int g = m & 3, j = 4 * T + (m >> 2);
            int col = g * 20 + j;
            if      (k < 20)  v = U[k * 80 + col];
            else if (k < 23)  v = W[(k - 20) * 80 + col];
            else if (k == 23) v = b[col];
            v *= (g == 2) ? (2.f * L2E) : L2E;
        } else {
            if      (k < 20)             v = 7.f * Wd[k];
            else if (k >= 24 && k < 28)  v = 1.f;
        }
        UT[idx] = f2bf(v);
    }

    const int gv0 = blockIdx.x * 64 + wv * 16;
    const int veh = gv0 + c;

    // ---- zero aug ----
    for (int idx = lane; idx < 640; idx += 64) aug[wv][idx] = 0;

    // ---- per-item constants: items j = 4T+q ----
    float wcn[5][4], wd7[5], w7b[5];
#pragma unroll
    for (int T = 0; T < 5; ++T) {
        int j = 4 * T + q;
#pragma unroll
        for (int g = 0; g < 4; ++g) {
            int col = g * 20 + j;
            wcn[T][g] = -(-0.001f * W[col] + 0.0025f * W[80 + col])
                      * ((g == 2) ? (2.f * L2E) : L2E);   // NEGATED coeff
        }
        float w7 = 7.f * Wd[j];
        wd7[T] = w7;
        w7b[T] = bf2f(f2bf(w7));
    }

    // ---- init: h0 -> aug, per-q res partial, exact acc partial ----
    float cst[5], hl[5];
    float rpart = 0.f, apart = 0.f;
#pragma unroll
    for (int T = 0; T < 5; ++T) {
        int j = 4 * T + q;
        float hv = h0[veh * H + j];
        cst[T] = c0[veh * H + j];
        hl[T] = hv;
        short hb = f2bf(hv);
        float hi = bf2f(hb);
        aug[wv][c * 40 + j] = hb;
        rpart = __builtin_fmaf(hv, wd7[T], rpart);
        rpart = __builtin_fmaf(-hi, w7b[T], rpart);
        apart = __builtin_fmaf(hv, wd7[T], apart);
    }
    aug[wv][c * 40 + 24 + q] = f2bf(rpart);   // per-q res slot (no shfl)
    apart += __shfl_xor(apart, 16); apart += __shfl_xor(apart, 32);

    float pos = inits[veh * 2 + 0];
    float spd = inits[veh * 2 + 1];
    {
        float a = apart + biasK;          // acc_{-1}, exact fp32
        pos -= 0.1f * a;                  // virtual lagged state
        spd -= 0.1f * a;
    }

    // ---- x~_0 write (lane q==0) ----
    const float2* lp0 = (const float2*)lead + (long)veh * NT;  // per-lane base
    float2 l2 = {0.f, 0.f};
    if (q == 0) {
        l2 = lp0[0];
        bf16x4 xs = { f2bf((l2.x - pos) * 0.01f), f2bf(spd * 0.025f),
                      f2bf(l2.y * 0.025f), f2bf(1.f) };
        *(bf16x4*)&aug[wv][c * 40 + 20] = xs;
    }
    __syncthreads();   // UT visibility; only barrier in the kernel

    // ---- loop-invariant A fragments ----
    bf16x8 A[6];
#pragma unroll
    for (int T = 0; T < 6; ++T)
        A[T] = *(const bf16x8*)&UT[(T * 16 + c) * 32 + q * 8];

    const int augB = c * 40 + q * 8;

    for (int t = 0; t < NT; ++t) {
        if (q == 0) {                        // prefetch lead[t+1] (uniform idx)
            int tn = (t < NT - 1) ? t + 1 : t;
            l2 = lp0[tn];
        }

        bf16x8 Bf = *(const bf16x8*)&aug[wv][augB];
        f32x4 zero = {0.f, 0.f, 0.f, 0.f};
        f32x4 z[6];
#pragma unroll
        for (int T = 0; T < 6; ++T)
            z[T] = __builtin_amdgcn_mfma_f32_16x16x32_bf16(A[T], Bf, zero, 0, 0, 0);

        // ---- acc_{t-1}: every lane, fp32-accurate (res in tile-5 dot) ----
        float acc = z[5][0] + biasK;
        pos = __builtin_fmaf(0.1f, acc, pos);
        spd = __builtin_fmaf(0.1f, acc, spd);
        if (q == 1 && t > 0) {
            float* orow = out + (size_t)(t - 1) * NVEH;   // uniform row ptr
            orow[veh] = pos;
        }
        if (q == 0) {   // x~ for step t+1 (lagged pos/spd + lead[t+1])
            bf16x4 xs = { f2bf((l2.x - pos) * 0.01f), f2bf(spd * 0.025f),
                          f2bf(l2.y * 0.025f), f2bf(1.f) };
            *(bf16x4*)&aug[wv][c * 40 + 20] = xs;
        }

        // ---- 5 items: gates lane-local; fma-folded sig args ----
        float rq = 0.f;
#pragma unroll
        for (int T = 0; T < 5; ++T) {
            float ei = EXP2(__builtin_fmaf(acc, wcn[T][0], -z[T][0]));
            float ef = EXP2(__builtin_fmaf(acc, wcn[T][1], -z[T][1]));
            float eg = EXP2(__builtin_fmaf(acc, wcn[T][2], -z[T][2]));
            float eo = EXP2(__builtin_fmaf(acc, wcn[T][3], -z[T][3]));
            float ii = RCP(1.f + ei);
            float ff = RCP(1.f + ef);
            float sg = RCP(1.f + eg);
            float oo = RCP(1.f + eo);
            float gg = __builtin_fmaf(2.f, sg, -1.f);          // tanh(g)
            float cc = __builtin_fmaf(ff, cst[T], ii * gg);
            cst[T] = cc;
            float ec = EXP2(N2L * cc);
            float st = RCP(1.f + ec);
            float hh = oo * __builtin_fmaf(2.f, st, -1.f);     // o*tanh(c)
            hl[T] = hh;
            unsigned u = __builtin_bit_cast(unsigned, hh);
            unsigned r = u + 0x7fffu + ((u >> 16) & 1u);       // RNE
            aug[wv][c * 40 + 4 * T + q] = (short)(r >> 16);
            float hi = __builtin_bit_cast(float, r & 0xffff0000u);
            rq = __builtin_fmaf(hh, wd7[T], rq);
            rq = __builtin_fmaf(-hi, w7b[T], rq);
        }
        aug[wv][c * 40 + 24 + q] = f2bf(rq);   // own slot, no shfl
    }

    // ---- tail: acc_255 exact from fp32 hl (shfl ok, once) ----
    float ap = 0.f;
#pragma unroll
    for (int T = 0; T < 5; ++T) ap = __builtin_fmaf(hl[T], wd7[T], ap);
    ap += __shfl_xor(ap, 16); ap += __shfl_xor(ap, 32);
    float accF = ap + biasK;
    if (q == 1) out[(size_t)(NT - 1) * NVEH + veh] = pos + 0.1f * accF;
    if (q == 2) out[(size_t)NT * NVEH + veh]       = spd + 0.1f * accF;

    // ---- final h, c ----
    const int oH = NT * NVEH + NVEH;
    const int oC = oH + NVEH * H;
#pragma unroll
    for (int T = 0; T < 5; ++T) {
        int j = 4 * T + q;
        out[oH + veh * H + j] = hl[T];
        out[oC + veh * H + j] = cst[T];
    }
}

extern "C" void kernel_launch(void* const* d_in, const int* in_sizes, int n_in,
                              void* d_out, int out_size, void* d_ws, size_t ws_size,
                              hipStream_t stream) {
    const float* lead  = (const float*)d_in[0];
    const float* inits = (const float*)d_in[1];
    const float* h0    = (const float*)d_in[2];
    const float* c0    = (const float*)d_in[3];
    const float* W     = (const float*)d_in[4];
    const float* U     = (const float*)d_in[5];
    const float* b     = (const float*)d_in[6];
    const float* Wd    = (const float*)d_in[7];
    const float* bd    = (const float*)d_in[8];
    float* out = (float*)d_out;

    rnncf_kernel<<<NVEH / 64, 256, 0, stream>>>(lead, inits, h0, c0, W, U, b, Wd, bd, out);
}

// Round 9
// 216.167 us; speedup vs baseline: 5.8569x; 1.2863x over previous
//
#include <hip/hip_runtime.h>

// RNN car-following: NVEH=16384, NT=256, H=20.
// R9: REGISTER-RESIDENT recurrence. Weights=A (static, any (gate,j)->row
// permutation). Items re-mapped so the B-frag is LANE-LOCAL: lane (q,c)
// owns items j=5q..5q+4 of vehicle c, and its B-frag k-window 8q..8q+7 is
// [h_{5q..5q+4}, res_q, x_q|one, 0] — assembled in registers each step.
// Tile 5 rows 4q are identical acc rows (7Wd @ h-slots, 1.0 @ res slots):
// every lane gets fp32-exact acc_{t-1} from z[5][0]; pos/spd tracked
// redundantly by all lanes. NO LDS / shuffles / barriers in the loop —
// R5..R8 showed wall = NT x serial chain and the LDS round-trip was the
// largest chain segment. Numerics = R8 (passed, absmax 1.0): bf16 U/W/b,
// fp32 wcn correction, hi/res acc split, per-q res partials.

#define NVEH 16384
#define NT   256
#define H    20

typedef float f32x4  __attribute__((ext_vector_type(4)));
typedef short bf16x8 __attribute__((ext_vector_type(8)));

#if __has_builtin(__builtin_amdgcn_exp2f)
#define EXP2(x) __builtin_amdgcn_exp2f(x)
#else
#define EXP2(x) __expf((x) * 0.69314718056f)
#endif
#define RCP(x) __builtin_amdgcn_rcpf(x)

__device__ __forceinline__ short f2bf(float f) {     // RNE float->bf16
    unsigned u = __builtin_bit_cast(unsigned, f);
    u += 0x7fffu + ((u >> 16) & 1u);
    return (short)(u >> 16);
}
__device__ __forceinline__ float bf2f(short s) {
    return __builtin_bit_cast(float, ((unsigned)(unsigned short)s) << 16);
}

__global__ __launch_bounds__(256, 1) void rnncf_kernel(
    const float* __restrict__ lead,   // (NVEH, NT, 2)
    const float* __restrict__ inits,  // (NVEH, 2)
    const float* __restrict__ h0,     // (NVEH, H)
    const float* __restrict__ c0,     // (NVEH, H)
    const float* __restrict__ W,      // (3, 80)
    const float* __restrict__ U,      // (20, 80)
    const float* __restrict__ b,      // (80,)
    const float* __restrict__ Wd,     // (20,)
    const float* __restrict__ bd,     // (1,)
    float* __restrict__ out)
{
    // UT: 6 tiles x 16 rows x 32 k (bf16). Gate tiles T=0..4: row m =
    // gate(m&3) of item j=5*(m>>2)+T, scaled log2e (2log2e for g).
    // k-content (kq=k>>3, ko=k&7): ko<5 -> U[5kq+ko][col]; ko==5 -> 0 (res);
    // ko==6 -> kq<3 ? W[kq][col] : b[col]; ko==7 -> 0.
    // Tile 5: rows with (m&3)==0: acc row: ko<5 -> 7*Wd[5kq+ko], ko==5 -> 1.0,
    // else 0 (bias added in fp32). Other rows 0.
    __shared__ __attribute__((aligned(16))) short UT[96 * 32];

    const int tid  = threadIdx.x;
    const int lane = tid & 63;
    const int q    = lane >> 4;       // k-window / item-group
    const int c    = lane & 15;       // vehicle column
    const float L2E = 1.44269504f;
    const float N2L = -2.f * L2E;
    const float bdv = bd[0];
    const float biasK = 7.f * bdv - 4.f;

    // ---- build UT ----
    for (int idx = tid; idx < 96 * 32; idx += 256) {
        int row = idx >> 5, k = idx & 31;
        int T = row >> 4, m = row & 15;
        int kq = k >> 3, ko = k & 7;
        float v = 0.f;
        if (T < 5) {
            int g = m & 3, j = 5 * (m >> 2) + T;
            int col = g * 20 + j;
            if      (ko < 5)             v = U[(5 * kq + ko) * 80 + col];
            else if (ko == 6 && kq < 3)  v = W[kq * 80 + col];
            else if (ko == 6)            v = b[col];
            v *= (g == 2) ? (2.f * L2E) : L2E;
        } else if ((m & 3) == 0) {
            if      (ko < 5)  v = 7.f * Wd[5 * kq + ko];
            else if (ko == 5) v = 1.f;
        }
        UT[idx] = f2bf(v);
    }

    const int veh = blockIdx.x * 64 + (tid >> 6) * 16 + c;

    // ---- per-item constants: items j = 5q+T, T=0..4 ----
    float wcn[5][4], wd7[5], w7b[5];
#pragma unroll
    for (int T = 0; T < 5; ++T) {
        int j = 5 * q + T;
#pragma unroll
        for (int g = 0; g < 4; ++g) {
            int col = g * 20 + j;
            wcn[T][g] = -(-0.001f * W[col] + 0.0025f * W[80 + col])
                      * ((g == 2) ? (2.f * L2E) : L2E);   // negated coeff
        }
        float w7 = 7.f * Wd[j];
        wd7[T] = w7;
        w7b[T] = bf2f(f2bf(w7));
    }

    // ---- init: h0 -> B-frag (registers), res partial, acc_{-1} ----
    bf16x8 Bf = {0, 0, 0, 0, 0, 0, 0, 0};
    float cst[5], hl[5];
    float rpart = 0.f, apart = 0.f;
#pragma unroll
    for (int T = 0; T < 5; ++T) {
        int j = 5 * q + T;
        float hv = h0[veh * H + j];
        cst[T] = c0[veh * H + j];
        hl[T] = hv;
        short hb = f2bf(hv);
        float hi = bf2f(hb);
        Bf[T] = hb;
        rpart = __builtin_fmaf(hv, wd7[T], rpart);
        rpart = __builtin_fmaf(-hi, w7b[T], rpart);
        apart = __builtin_fmaf(hv, wd7[T], apart);
    }
    Bf[5] = f2bf(rpart);
    apart += __shfl_xor(apart, 16);
    apart += __shfl_xor(apart, 32);

    float pos = inits[veh * 2 + 0];
    float spd = inits[veh * 2 + 1];
    {
        float a = apart + biasK;          // acc_{-1}, exact fp32
        pos -= 0.1f * a;                  // virtual lagged state
        spd -= 0.1f * a;
    }

    // ---- x~_0 and lead pipeline (depth 2) ----
    const float2* lp0 = (const float2*)lead + (long)veh * NT;
    {
        float2 lu = lp0[0];
        float xv = (q == 0) ? (lu.x - pos) * 0.01f
                 : (q == 1) ? spd * 0.025f
                            : lu.y * 0.025f;
        if (q < 3) Bf[6] = f2bf(xv);
        else       Bf[6] = (short)0x3F80;   // one-slot (1.0 bf16)
    }
    float2 lA = lp0[1];
    float2 lB = lp0[2];

    __syncthreads();   // UT visibility; only barrier in the kernel

    // ---- loop-invariant A fragments (row c, k-slice q) ----
    bf16x8 A[6];
#pragma unroll
    for (int T = 0; T < 6; ++T)
        A[T] = *(const bf16x8*)&UT[(T * 16 + c) * 32 + q * 8];

    for (int t = 0; t < NT; ++t) {
        float2 lu = lA;                   // lead[t+1], loaded 2 iters ago
        lA = lB;
        int tn = t + 3; tn = (tn < NT) ? tn : NT - 1;
        lB = lp0[tn];                     // consumed 2 iters from now

        f32x4 zero = {0.f, 0.f, 0.f, 0.f};
        f32x4 z[6];
#pragma unroll
        for (int T = 0; T < 6; ++T)
            z[T] = __builtin_amdgcn_mfma_f32_16x16x32_bf16(A[T], Bf, zero, 0, 0, 0);

        // ---- acc_{t-1}: every lane, fp32-accurate ----
        float acc = z[5][0] + biasK;
        pos = __builtin_fmaf(0.1f, acc, pos);
        spd = __builtin_fmaf(0.1f, acc, spd);
        if (q == 1 && t > 0)
            out[(size_t)(t - 1) * NVEH + veh] = pos;   // coalesced

        // ---- x~_{t+1} into own B-frag slot ----
        {
            float xv = (q == 0) ? (lu.x - pos) * 0.01f
                     : (q == 1) ? spd * 0.025f
                                : lu.y * 0.025f;
            if (q < 3) Bf[6] = f2bf(xv);
        }

        // ---- 5 items (j=5q+T): gates lane-local in z[T][0..3] ----
        float rq = 0.f;
#pragma unroll
        for (int T = 0; T < 5; ++T) {
            float ei = EXP2(__builtin_fmaf(acc, wcn[T][0], -z[T][0]));
            float ef = EXP2(__builtin_fmaf(acc, wcn[T][1], -z[T][1]));
            float eg = EXP2(__builtin_fmaf(acc, wcn[T][2], -z[T][2]));
            float eo = EXP2(__builtin_fmaf(acc, wcn[T][3], -z[T][3]));
            float ii = RCP(1.f + ei);
            float ff = RCP(1.f + ef);
            float sg = RCP(1.f + eg);
            float oo = RCP(1.f + eo);
            float gg = __builtin_fmaf(2.f, sg, -1.f);          // tanh(g)
            float cc = __builtin_fmaf(ff, cst[T], ii * gg);
            cst[T] = cc;
            float ec = EXP2(N2L * cc);
            float st = RCP(1.f + ec);
            float hh = oo * __builtin_fmaf(2.f, st, -1.f);     // o*tanh(c)
            hl[T] = hh;
            unsigned u = __builtin_bit_cast(unsigned, hh);
            unsigned r = u + 0x7fffu + ((u >> 16) & 1u);       // RNE
            Bf[T] = (short)(r >> 16);
            float hi = __builtin_bit_cast(float, r & 0xffff0000u);
            rq = __builtin_fmaf(hh, wd7[T], rq);
            rq = __builtin_fmaf(-hi, w7b[T], rq);
        }
        Bf[5] = f2bf(rq);
    }

    // ---- tail: acc_255 exact from fp32 hl ----
    float ap = 0.f;
#pragma unroll
    for (int T = 0; T < 5; ++T) ap = __builtin_fmaf(hl[T], wd7[T], ap);
    ap += __shfl_xor(ap, 16);
    ap += __shfl_xor(ap, 32);
    float accF = ap + biasK;
    if (q == 1) out[(size_t)(NT - 1) * NVEH + veh] = pos + 0.1f * accF;
    if (q == 2) out[(size_t)NT * NVEH + veh]       = spd + 0.1f * accF;

    // ---- final h, c ----
    const int oH = NT * NVEH + NVEH;
    const int oC = oH + NVEH * H;
#pragma unroll
    for (int T = 0; T < 5; ++T) {
        int j = 5 * q + T;
        out[oH + veh * H + j] = hl[T];
        out[oC + veh * H + j] = cst[T];
    }
}

extern "C" void kernel_launch(void* const* d_in, const int* in_sizes, int n_in,
                              void* d_out, int out_size, void* d_ws, size_t ws_size,
                              hipStream_t stream) {
    const float* lead  = (const float*)d_in[0];
    const float* inits = (const float*)d_in[1];
    const float* h0    = (const float*)d_in[2];
    const float* c0    = (const float*)d_in[3];
    const float* W     = (const float*)d_in[4];
    const float* U     = (const float*)d_in[5];
    const float* b     = (const float*)d_in[6];
    const float* Wd    = (const float*)d_in[7];
    const float* bd    = (const float*)d_in[8];
    float* out = (float*)d_out;

    rnncf_kernel<<<NVEH / 64, 256, 0, stream>>>(lead, inits, h0, c0, W, U, b, Wd, bd, out);
}